// Round 1
// baseline (297.043 us; speedup 1.0000x reference)
//
#include <hip/hip_runtime.h>
#include <hip/hip_bf16.h>

typedef __attribute__((ext_vector_type(8))) short short8;
typedef __attribute__((ext_vector_type(4))) float floatx4;

#define N_ROWS 8192
#define C_DIM  128
#define KSCALE 14.426950408889634f   /* 10 * log2(e) */
#define LN2    0.6931471805599453f

__device__ __forceinline__ unsigned short f2bf(float f) {
    union { float f; unsigned int u; } x; x.f = f;
    unsigned int r = x.u + 0x7FFFu + ((x.u >> 16) & 1u);
    return (unsigned short)(r >> 16);
}

// One wave per row: L2-normalize 128 f32 -> 128 bf16
__global__ __launch_bounds__(256) void norm_kernel(
    const float* __restrict__ img, const float* __restrict__ mol,
    unsigned short* __restrict__ W)
{
    int wave = threadIdx.x >> 6, lane = threadIdx.x & 63;
    int row = blockIdx.x * 4 + wave;               // 0..16383
    const float* src = (row < N_ROWS) ? (img + (size_t)row * C_DIM)
                                      : (mol + (size_t)(row - N_ROWS) * C_DIM);
    float2 v = *reinterpret_cast<const float2*>(src + lane * 2);
    float ss = v.x * v.x + v.y * v.y;
    #pragma unroll
    for (int m = 1; m < 64; m <<= 1) ss += __shfl_xor(ss, m);
    float inv = rsqrtf(ss);                        // ||x|| ~ sqrt(128), eps moot
    unsigned short* dst = W + (size_t)row * C_DIM;
    dst[lane * 2]     = f2bf(v.x * inv);
    dst[lane * 2 + 1] = f2bf(v.y * inv);
}

__device__ __forceinline__ void load_btile(short8 (&bf)[2][4],
    const unsigned short* __restrict__ Y, int jb, int l15, int lg)
{
    #pragma unroll
    for (int n = 0; n < 2; ++n)
        #pragma unroll
        for (int k = 0; k < 4; ++k)
            bf[n][k] = *reinterpret_cast<const short8*>(
                Y + (size_t)(jb + n * 16 + l15) * C_DIM + k * 32 + lg * 8);
}

__device__ __forceinline__ void compute_tile(
    const short8 (&af)[2][4], const short8 (&bf)[2][4],
    int rbase, int jb, int l15, int lg, bool diagpass,
    float (&se)[2][4], float& pos)
{
    #pragma unroll
    for (int m = 0; m < 2; ++m) {
        #pragma unroll
        for (int n = 0; n < 2; ++n) {
            floatx4 acc = {0.f, 0.f, 0.f, 0.f};
            #pragma unroll
            for (int k = 0; k < 4; ++k)
                acc = __builtin_amdgcn_mfma_f32_16x16x32_bf16(
                          af[m][k], bf[n][k], acc, 0, 0, 0);
            int gc  = jb + n * 16 + l15;
            int gr0 = rbase + m * 16 + lg * 4;
            #pragma unroll
            for (int r = 0; r < 4; ++r) {
                float v = acc[r];                       // dot of unit vectors
                float e = __builtin_amdgcn_exp2f(v * KSCALE - KSCALE);
                bool d = ((gr0 + r) == gc);
                if (d) { if (diagpass) pos += v; e = 0.f; }
                se[m][r] += e;
            }
        }
    }
}

// grid.x: 64 row-blocks (128 rows each), grid.y: 4 passes (AA, AB, BB, BA)
__global__ __launch_bounds__(256) void pass_kernel(
    const unsigned short* __restrict__ W, float* __restrict__ out)
{
    int pass = blockIdx.y;
    const unsigned short* X = (pass < 2) ? W : W + (size_t)N_ROWS * C_DIM;
    const unsigned short* Y = (pass == 1 || pass == 2)
                                ? W + (size_t)N_ROWS * C_DIM : W;
    int lane = threadIdx.x & 63, wave = threadIdx.x >> 6;
    int l15 = lane & 15, lg = lane >> 4;
    int rbase = blockIdx.x * 128 + wave * 32;

    short8 af[2][4];
    #pragma unroll
    for (int m = 0; m < 2; ++m)
        #pragma unroll
        for (int k = 0; k < 4; ++k)
            af[m][k] = *reinterpret_cast<const short8*>(
                X + (size_t)(rbase + m * 16 + l15) * C_DIM + k * 32 + lg * 8);

    float se[2][4] = {{0.f,0.f,0.f,0.f},{0.f,0.f,0.f,0.f}};
    float pos = 0.f;
    bool diagpass = (pass == 1);

    short8 bA[2][4], bB[2][4];
    load_btile(bA, Y, 0, l15, lg);
    for (int jb = 0; jb < N_ROWS; jb += 64) {
        load_btile(bB, Y, jb + 32, l15, lg);
        compute_tile(af, bA, rbase, jb, l15, lg, diagpass, se, pos);
        load_btile(bA, Y, (jb + 64) & (N_ROWS - 1), l15, lg);
        compute_tile(af, bB, rbase, jb + 32, l15, lg, diagpass, se, pos);
    }

    float part = diagpass ? (-10.0f * pos) : 0.f;    // positive term: -sim_01[i][i]
    #pragma unroll
    for (int m = 0; m < 2; ++m)
        #pragma unroll
        for (int r = 0; r < 4; ++r) {
            float s = se[m][r];
            s += __shfl_xor(s, 1);
            s += __shfl_xor(s, 2);
            s += __shfl_xor(s, 4);
            s += __shfl_xor(s, 8);
            if (l15 == 0)
                part += 0.5f * (LN2 * __builtin_amdgcn_logf(s) + 10.0f);
        }
    #pragma unroll
    for (int m = 1; m < 64; m <<= 1) part += __shfl_xor(part, m);
    if (lane == 0) atomicAdd(out, part * (1.0f / N_ROWS));
}

extern "C" void kernel_launch(void* const* d_in, const int* in_sizes, int n_in,
                              void* d_out, int out_size, void* d_ws, size_t ws_size,
                              hipStream_t stream)
{
    const float* img = (const float*)d_in[0];
    const float* mol = (const float*)d_in[1];
    float* out = (float*)d_out;
    unsigned short* W = (unsigned short*)d_ws;      // A bf16 | B bf16 (4 MB)

    hipMemsetAsync(d_out, 0, sizeof(float), stream);
    norm_kernel<<<dim3(N_ROWS * 2 / 4), 256, 0, stream>>>(img, mol, W);
    pass_kernel<<<dim3(N_ROWS / 128, 4), 256, 0, stream>>>(W, out);
}